// Round 4
// baseline (61.541 us; speedup 1.0000x reference)
//
#include <hip/hip_runtime.h>

// RoPE, fp32, d_k=128, theta=10000.
// out[..,2k]   = cos(a)*x[..,2k] - sin(a)*x[..,2k+1]
// out[..,2k+1] = sin(a)*x[..,2k] + cos(a)*x[..,2k+1],  a = pos[s]*theta^(-k/64)
//
// Memory-bound streaming op (16.8 MB total). Each thread handles TWO float4s
// (4 rotation pairs), fully coalesced 16B/lane, nontemporal loads/stores to
// stream past L2 write-allocate. Trig via HW v_sin/v_cos in the revolutions
// domain with explicit fract range reduction (|rev| up to ~651).
//
// NB: nontemporal builtins need a native clang vector type, not HIP float4.

typedef float vfloat4 __attribute__((ext_vector_type(4)));

#define D_K 128

__global__ __launch_bounds__(256) void rope_kernel(
    const vfloat4* __restrict__ x4,
    const int*     __restrict__ pos,
    vfloat4*       __restrict__ out4,
    int n4, int seq)
{
    const float INV_2PI = 0.15915494309189535f;
    const float L       = 0.20762050593046014f;   // log2(10000)/64
    const float STEP    = 0.86596432336006535f;   // 10000^(-1/64)

    int t = blockIdx.x * blockDim.x + threadIdx.x;

    #pragma unroll
    for (int u = 0; u < 2; ++u) {
        int i = t + u * (gridDim.x * blockDim.x);   // stride-apart: stays coalesced
        if (i >= n4) break;

        int flat = i * 4;
        int d    = flat & (D_K - 1);
        int s    = (flat >> 7) % seq;               // /D_K
        float p_rev = (float)pos[s] * INV_2PI;

        int   k0 = d >> 1;
        float f0 = __builtin_amdgcn_exp2f(-L * (float)k0);
        float f1 = f0 * STEP;

        float r0 = __builtin_amdgcn_fractf(p_rev * f0);
        float r1 = __builtin_amdgcn_fractf(p_rev * f1);
        float s0 = __builtin_amdgcn_sinf(r0);
        float c0 = __builtin_amdgcn_cosf(r0);
        float s1 = __builtin_amdgcn_sinf(r1);
        float c1 = __builtin_amdgcn_cosf(r1);

        vfloat4 v = __builtin_nontemporal_load(x4 + i);
        vfloat4 o;
        o.x = c0 * v.x - s0 * v.y;
        o.y = s0 * v.x + c0 * v.y;
        o.z = c1 * v.z - s1 * v.w;
        o.w = s1 * v.z + c1 * v.w;
        __builtin_nontemporal_store(o, out4 + i);
    }
}

extern "C" void kernel_launch(void* const* d_in, const int* in_sizes, int n_in,
                              void* d_out, int out_size, void* d_ws, size_t ws_size,
                              hipStream_t stream) {
    const vfloat4* x4  = (const vfloat4*)d_in[0];
    const int*     pos = (const int*)d_in[1];
    vfloat4*       o4  = (vfloat4*)d_out;

    int n   = in_sizes[0];       // 4*4096*128 fp32 elements
    int seq = in_sizes[1];       // 4096
    int n4  = n / 4;             // 524288 float4s

    int block   = 256;
    int threads = (n4 + 1) / 2;  // 2 float4s per thread
    int grid    = (threads + block - 1) / block;
    rope_kernel<<<grid, block, 0, stream>>>(x4, pos, o4, n4, seq);
}